// Round 11
// baseline (121.705 us; speedup 1.0000x reference)
//
#include <hip/hip_runtime.h>

// out[t, j] = W[j, x[t]] + b[j]
//   x : [16384] int32, W : [1024, 50257] f32 row-major, b : [1024] f32
//   out: [16384, 1024] f32
//
// R2..R10 lesson: EVERY lane-divergent W access costs ~4.5cyc at the TA
// regardless of cache hits (R10 fetched each line once yet still ~12.9M
// divergent 16B lane-requests -> ~95us). The fix is wave-CONTIGUOUS W
// reads only.
// R11: tile W itself. Block = (super-bucket: 512 vocab slots) x (16 js).
// Stage: 16 rows x 2KB contiguous each -> pure coalesced streaming; every
// W element read exactly once grid-wide (~203MB sequential). LDS slab
// 512x16 in float4 units, stride 17 units: ds_write_b128 lands uniform
// across banks; serve reads ~2-way. Serve: tokens of the super (coarse
// 99-bucket counting sort), 16 lanes/token: read slab[u][jj], write a
// contiguous 64B segment of out[t] (4 segments per wave-store, ~1M
// segments total ~ 7us of divergence). No register slabs (R9 scratch
// lesson), one barrier.

#define VOCAB 50257
#define DIM   1024
#define VBLK  512
#define NSUP  ((VOCAB + VBLK - 1) / VBLK)   // 99 super-buckets
#define NJT   (DIM / 16)                    // 64 j-tiles
#define SLAB_UNITS (128 * 17)               // float4 units: c in [0,128), pad 1

// ---------- sort pipeline (counting sort by v>>9) ----------

__global__ void zero_counts_kernel(int* __restrict__ counts, int n) {
    int i = blockIdx.x * blockDim.x + threadIdx.x;
    if (i < n) counts[i] = 0;
}

__global__ void hist_kernel(const int* __restrict__ x, int n, int* __restrict__ counts) {
    int i = blockIdx.x * blockDim.x + threadIdx.x;
    if (i < n) atomicAdd(&counts[x[i] >> 9], 1);
}

// one wave: shfl inclusive scan over 99 buckets (2 per lane)
__global__ __launch_bounds__(64) void scan_kernel(const int* __restrict__ counts,
                                                  int* __restrict__ offs) {
    const int l = threadIdx.x;
    int c0 = (2 * l     < NSUP) ? counts[2 * l]     : 0;
    int c1 = (2 * l + 1 < NSUP) ? counts[2 * l + 1] : 0;
    int s = c0 + c1;
    for (int d = 1; d < 64; d <<= 1) {
        int y = __shfl_up(s, d);
        if (l >= d) s += y;
    }
    const int excl = s - c0 - c1;
    if (2 * l     < NSUP) offs[2 * l]     = excl;
    if (2 * l + 1 < NSUP) offs[2 * l + 1] = excl + c0;
}

// offs consumed as running cursors (recomputed every call). Intra-bucket
// order nondeterministic but out[t] depends only on t's own v ->
// deterministic OUTPUT. Packs (v << 16) | t. After: offs[g] = bucket end.
__global__ void scatter_kernel(const int* __restrict__ x, int n,
                               int* __restrict__ offs, int* __restrict__ order) {
    int i = blockIdx.x * blockDim.x + threadIdx.x;
    if (i < n) {
        unsigned v = (unsigned)x[i];
        int pos = atomicAdd(&offs[v >> 9], 1);
        order[pos] = (int)((v << 16) | (unsigned)i);
    }
}

// ---------- tiled gather: block = (super s) x (j-tile jt) ----------
__global__ __launch_bounds__(256) void tile_gather_kernel(
    const float* __restrict__ W,
    const float* __restrict__ bias,
    const int* __restrict__ order,
    const int* __restrict__ ends,
    float* __restrict__ out)
{
    extern __shared__ float4 slab4[];        // SLAB_UNITS float4 = 34816 B
    float* const slab_f = (float*)slab4;

    const int bid = blockIdx.x;
    const int s  = bid >> 6;                 // super-bucket 0..98
    const int jt = bid & 63;                 // j-tile 0..63
    const int end = ends[s];
    const int start = (s == 0) ? 0 : ends[s - 1];
    if (end == start) return;                // uniform -> safe

    const int j0 = jt * 16;
    const int vbase = s * VBLK;
    const int tid = threadIdx.x;

    // ---- stage: 16 rows x 512 floats, fully coalesced float4 loads ----
    // f = tid + k*256 in [0,2048): row = f>>7 (0..15), c = f&127 (float4 col)
    const bool lastS = (s == NSUP - 1);      // block-uniform
#pragma unroll
    for (int k = 0; k < 8; ++k) {
        const int f = tid + k * 256;
        const int row = f >> 7;
        const int c = f & 127;
        const float* src = W + (size_t)(j0 + row) * VOCAB + vbase + c * 4;
        float4 a;
        if (!lastS) {
            a = *reinterpret_cast<const float4*>(src);
        } else {
            const int vb = vbase + c * 4;
            a.x = (vb + 0 < VOCAB) ? src[0] : 0.f;
            a.y = (vb + 1 < VOCAB) ? src[1] : 0.f;
            a.z = (vb + 2 < VOCAB) ? src[2] : 0.f;
            a.w = (vb + 3 < VOCAB) ? src[3] : 0.f;
        }
        // unit idx = c*17 + row : b128 writes tile all 32 banks uniformly
        slab4[c * 17 + row] = a;
    }
    __syncthreads();

    // ---- serve: 16 tokens per round, 16 lanes per token ----
    const int lane_t = tid >> 4;             // which of 16 tokens this round
    const int jj = tid & 15;                 // j within tile
    const float bb = bias[j0 + jj];

    for (int i0 = start; i0 < end; i0 += 16) {
        const int i = i0 + lane_t;
        if (i < end) {
            const unsigned pk = (unsigned)order[i];
            const int t = (int)(pk & 0xFFFFu);
            const int u = (int)(pk >> 16) - vbase;   // 0..511
            const int c = u >> 2, e = u & 3;
            const float wv = slab_f[(c * 17 + jj) * 4 + e];
            out[(size_t)t * DIM + j0 + jj] = wv + bb;  // 64B contiguous/token
        }
    }
}

// fallback (round-1 kernel) if workspace too small / n too large for packing
__global__ __launch_bounds__(256) void gather_direct_kernel(
    const int* __restrict__ x,
    const float* __restrict__ W,
    const float* __restrict__ bias,
    float* __restrict__ out)
{
    const int t = blockIdx.x;
    const int v = x[t];
    const int j0 = threadIdx.x * 4;
    float4 rr;
    rr.x = W[(size_t)(j0 + 0) * VOCAB + v];
    rr.y = W[(size_t)(j0 + 1) * VOCAB + v];
    rr.z = W[(size_t)(j0 + 2) * VOCAB + v];
    rr.w = W[(size_t)(j0 + 3) * VOCAB + v];
    const float4 bb = *reinterpret_cast<const float4*>(bias + j0);
    rr.x += bb.x; rr.y += bb.y; rr.z += bb.z; rr.w += bb.w;
    *reinterpret_cast<float4*>(out + (size_t)t * DIM + j0) = rr;
}

extern "C" void kernel_launch(void* const* d_in, const int* in_sizes, int n_in,
                              void* d_out, int out_size, void* d_ws, size_t ws_size,
                              hipStream_t stream) {
    const int*   x    = (const int*)d_in[0];
    const float* W    = (const float*)d_in[1];
    const float* bias = (const float*)d_in[2];
    float*       out  = (float*)d_out;

    const int n = in_sizes[0];           // 16384 tokens

    const size_t need = (size_t)(2 * NSUP + n) * sizeof(int);
    if (ws_size < need || n > 65536) {   // packing uses 16 bits for token id
        gather_direct_kernel<<<n, 256, 0, stream>>>(x, W, bias, out);
        return;
    }

    int* counts = (int*)d_ws;            // [NSUP]
    int* offs   = counts + NSUP;         // [NSUP] -> per-bucket end offsets
    int* order  = offs + NSUP;           // [n] packed (v<<16 | t)

    const int tb = 256;
    zero_counts_kernel<<<1, tb, 0, stream>>>(counts, NSUP);
    hist_kernel<<<(n + tb - 1) / tb, tb, 0, stream>>>(x, n, counts);
    scan_kernel<<<1, 64, 0, stream>>>(counts, offs);
    scatter_kernel<<<(n + tb - 1) / tb, tb, 0, stream>>>(x, n, offs, order);

    const size_t slab_bytes = SLAB_UNITS * sizeof(float4);   // 34816
    tile_gather_kernel<<<NSUP * NJT, tb, slab_bytes, stream>>>(W, bias, order, offs, out);
}

// Round 12
// 64.836 us; speedup vs baseline: 1.8771x; 1.8771x over previous
//
#include <hip/hip_runtime.h>

// out[t, j] = W[j, x[t]] + b[j]
//   x : [16384] int32, W : [1024, 50257] f32 row-major, b : [1024] f32
//   out: [16384, 1024] f32
//
// R2..R11: cost model = ~4.5cyc per address-divergent SEGMENT per load
// instruction. All prior rounds had lanes spanning different j-rows
// (201KB stride) -> 64 segments/instr, 16.8M total, ~120us wall.
// R12: lanes = 64 SORTED tokens, j wave-uniform per instruction. 64
// sorted-adjacent tokens span ~196 vocab slots = ~13 distinct 64B lines
// -> wave coalescer merges to ~13 transactions/instr: 3.4M total (5x).
// Output transposed via LDS tile [64 tok][65] (2-way = free) so stores
// stay 64B-coalesced (16 segments/instr). Loads 8-deep + sched_barrier
// (R6-proven keeps them in flight). 2048 blocks, 8/CU.

#define VOCAB 50257
#define DIM   1024
#define NBUCK ((VOCAB + 15) >> 4)     // 3142 line-groups
#define NXCD  8
#define TPB   64                      // tokens per block
#define JSL   128                     // j-slice per block
#define NJS   (DIM / JSL)             // 8 j-slices
#define TSTR  65                      // LDS tile stride (floats)

// ---------- sort pipeline (counting sort by v>>4) ----------

__global__ void zero_counts_kernel(int* __restrict__ counts, int n) {
    int i = blockIdx.x * blockDim.x + threadIdx.x;
    if (i < n) counts[i] = 0;
}

__global__ void hist_kernel(const int* __restrict__ x, int n, int* __restrict__ counts) {
    int i = blockIdx.x * blockDim.x + threadIdx.x;
    if (i < n) atomicAdd(&counts[x[i] >> 4], 1);
}

__global__ __launch_bounds__(256) void scan_kernel(const int* __restrict__ counts,
                                                   int* __restrict__ offs) {
    const int CHUNK = (NBUCK + 255) / 256;   // 13
    __shared__ int lds[256];
    const int tid = threadIdx.x;
    const int base = tid * CHUNK;
    int local[CHUNK];
    int s = 0;
#pragma unroll
    for (int k = 0; k < CHUNK; ++k) {
        int idx = base + k;
        int c = (idx < NBUCK) ? counts[idx] : 0;
        local[k] = s;
        s += c;
    }
    lds[tid] = s;
    __syncthreads();
    if (tid == 0) {
        int run = 0;
        for (int i = 0; i < 256; ++i) { int c = lds[i]; lds[i] = run; run += c; }
    }
    __syncthreads();
    const int boff = lds[tid];
#pragma unroll
    for (int k = 0; k < CHUNK; ++k) {
        int idx = base + k;
        if (idx < NBUCK) offs[idx] = boff + local[k];
    }
}

// Packs (v << 16) | t. Intra-bucket order nondeterministic but out[t]
// depends only on t's own v -> deterministic OUTPUT.
__global__ void scatter_kernel(const int* __restrict__ x, int n,
                               int* __restrict__ offs, int* __restrict__ order) {
    int i = blockIdx.x * blockDim.x + threadIdx.x;
    if (i < n) {
        int v = x[i];
        int pos = atomicAdd(&offs[v >> 4], 1);
        order[pos] = (v << 16) | i;
    }
}

// ---------- gather: lanes = sorted tokens, j uniform per instr ----------
__global__ __launch_bounds__(256) void lane_sorted_gather(
    const float* __restrict__ W,
    const float* __restrict__ bias,
    const int* __restrict__ order,
    float* __restrict__ out,
    int n, int q, int r)   // q = nblk/8, r = nblk%8 (bijective XCD chunking)
{
    extern __shared__ float lds[];
    float* tile = lds;                       // [64][TSTR]
    int* tTok = (int*)(lds + TPB * TSTR);    // [64]

    const int bid = blockIdx.x;
    const int xcd = bid & (NXCD - 1);
    const int idx = bid >> 3;
    const int chunk_base = (xcd < r) ? xcd * (q + 1) : r * (q + 1) + (xcd - r) * q;
    const int L = chunk_base + idx;          // logical: consecutive L on one XCD
    const int g  = L >> 3;                   // token group (groups contiguous/XCD)
    const int js = L & 7;                    // j-slice 0..7

    const int tid = threadIdx.x;
    const int wave = tid >> 6;
    const int lane = tid & 63;

    const int t0 = g * TPB;
    const int cnt = min(TPB, n - t0);

    const unsigned pk = (unsigned)order[t0 + (lane < cnt ? lane : 0)]; // coalesced
    const int vl = (int)(pk >> 16);          // this lane's token's v (sorted)
    if (wave == 0) tTok[lane] = (int)(pk & 0xFFFFu);

    const int jb0 = js * JSL;
    const float* __restrict__ Wv = W + vl;   // per-lane column base

    const int tok = tid >> 2;                // store phase: token 0..63
    const int qq = tid & 3;                  // quad within 64-float chunk

#pragma unroll
    for (int ch = 0; ch < JSL / 64; ++ch) {  // 2 chunks of 64 j
        const int jb = jb0 + ch * 64 + wave * 16;  // this wave's 16 js

        // ---- load 8, fence, ds_write 8 (x2): lanes sorted -> ~13 segs/instr
        float a[8];
#pragma unroll
        for (int i = 0; i < 8; ++i)
            a[i] = Wv[(size_t)(jb + i) * VOCAB];
        __builtin_amdgcn_sched_barrier(0);
#pragma unroll
        for (int i = 0; i < 8; ++i)
            tile[lane * TSTR + wave * 16 + i] = a[i];

        float b[8];
#pragma unroll
        for (int i = 0; i < 8; ++i)
            b[i] = Wv[(size_t)(jb + 8 + i) * VOCAB];
        __builtin_amdgcn_sched_barrier(0);
#pragma unroll
        for (int i = 0; i < 8; ++i)
            tile[lane * TSTR + wave * 16 + 8 + i] = b[i];

        __syncthreads();                     // tile (and tTok on ch=0) ready

        // ---- store: 4 threads/token; instr k writes contiguous 64B/token
        if (tok < cnt) {
            const int t = tTok[tok];
            float* __restrict__ dst = out + (size_t)t * DIM + jb0 + ch * 64;
#pragma unroll
            for (int k = 0; k < 4; ++k) {
                const int jloc = k * 16 + qq * 4;
                float4 w4 = *reinterpret_cast<const float4*>(&tile[tok * TSTR + jloc]);
                const float4 b4 = *reinterpret_cast<const float4*>(&bias[jb0 + ch * 64 + jloc]);
                w4.x += b4.x; w4.y += b4.y; w4.z += b4.z; w4.w += b4.w;
                *reinterpret_cast<float4*>(dst + jloc) = w4;
            }
        }
        __syncthreads();                     // before next chunk overwrites tile
    }
}

// fallback (round-1 kernel) if workspace too small / n too large for packing
__global__ __launch_bounds__(256) void gather_direct_kernel(
    const int* __restrict__ x,
    const float* __restrict__ W,
    const float* __restrict__ bias,
    float* __restrict__ out)
{
    const int t = blockIdx.x;
    const int v = x[t];
    const int j0 = threadIdx.x * 4;
    float4 rr;
    rr.x = W[(size_t)(j0 + 0) * VOCAB + v];
    rr.y = W[(size_t)(j0 + 1) * VOCAB + v];
    rr.z = W[(size_t)(j0 + 2) * VOCAB + v];
    rr.w = W[(size_t)(j0 + 3) * VOCAB + v];
    const float4 bb = *reinterpret_cast<const float4*>(bias + j0);
    rr.x += bb.x; rr.y += bb.y; rr.z += bb.z; rr.w += bb.w;
    *reinterpret_cast<float4*>(out + (size_t)t * DIM + j0) = rr;
}

extern "C" void kernel_launch(void* const* d_in, const int* in_sizes, int n_in,
                              void* d_out, int out_size, void* d_ws, size_t ws_size,
                              hipStream_t stream) {
    const int*   x    = (const int*)d_in[0];
    const float* W    = (const float*)d_in[1];
    const float* bias = (const float*)d_in[2];
    float*       out  = (float*)d_out;

    const int n = in_sizes[0];           // 16384 tokens

    const size_t need = (size_t)(2 * NBUCK + n) * sizeof(int);
    if (ws_size < need || n > 65536) {   // packing uses 16 bits for token id
        gather_direct_kernel<<<n, 256, 0, stream>>>(x, W, bias, out);
        return;
    }

    int* counts = (int*)d_ws;            // [NBUCK]
    int* offs   = counts + NBUCK;        // [NBUCK]
    int* order  = offs + NBUCK;          // [n] packed (v<<16 | t)

    const int tb = 256;
    zero_counts_kernel<<<(NBUCK + tb - 1) / tb, tb, 0, stream>>>(counts, NBUCK);
    hist_kernel<<<(n + tb - 1) / tb, tb, 0, stream>>>(x, n, counts);
    scan_kernel<<<1, tb, 0, stream>>>(counts, offs);
    scatter_kernel<<<(n + tb - 1) / tb, tb, 0, stream>>>(x, n, offs, order);

    const int ngroups = (n + TPB - 1) / TPB;     // 256
    const int nblk = ngroups * NJS;              // 2048
    const int q = nblk / NXCD, r = nblk % NXCD;
    const size_t lds_bytes = (TPB * TSTR) * sizeof(float) + TPB * sizeof(int);
    lane_sorted_gather<<<nblk, 256, lds_bytes, stream>>>(W, bias, order, out, n, q, r);
}